// Round 17
// baseline (317.483 us; speedup 1.0000x reference)
//
#include <hip/hip_runtime.h>
#include <hip/hip_bf16.h>

// PseudoTripletLoss on MI355X (gfx950) — fused real path + epilogue-bisect ablations
// loss*n(n-1) = sum_{i<j} relu(s-0.1)  [label-blind GEMM blocks]
//             + sum_{i<j,same} ((1-s) - relu(s-0.1))  [corr blocks, same dispatch]
// Ablations (x reps, scratch): V1 full | V2 acc-read-only | V3 one-read/frag |
// V4 no-barrier | V5 no-stage.

typedef __attribute__((ext_vector_type(8))) short short8;
typedef __attribute__((ext_vector_type(4))) float f32x4;

#define DIM 128
#define MARGIN 0.1f
#define CHUNK 4
#define NLAB 100
#define CAP 128

typedef const void __attribute__((address_space(1)))* gas_ptr;
typedef void __attribute__((address_space(3)))* las_ptr;

static __device__ __forceinline__ void load16_to_lds(const void* g, void* l) {
    __builtin_amdgcn_global_load_lds((gas_ptr)g, (las_ptr)l, 16, 0, 0);
}

static __device__ __forceinline__ unsigned short f2bf(float f) {
    unsigned int u = __builtin_bit_cast(unsigned int, f);
    u += 0x7FFFu + ((u >> 16) & 1u);
    return (unsigned short)(u >> 16);
}

// 512-thread staging of a 64x128 bf16 tile; lane-linear LDS dest; XOR
// involution on the SOURCE column.
static __device__ __forceinline__ void stage64(const short* __restrict__ en, int row0,
                                               short* buf, int tid) {
    const char* src = (const char*)(en + (size_t)row0 * DIM);
    char* dst = (char*)buf;
    const int r_lo = tid >> 4;
    const int s    = tid & 15;
    #pragma unroll
    for (int p = 0; p < 2; ++p) {
        const int r  = p * 32 + r_lo;
        const int sc = (s ^ (r & 7)) << 4;
        load16_to_lds(src + (size_t)r * 256 + sc, dst + r * 256 + s * 16);
    }
}

static __device__ __forceinline__ short8 read_frag(const short* buf, int row, int slot) {
    const int ps = slot ^ (row & 7);
    return *(const short8*)(buf + row * DIM + ps * 8);
}

// ---------------- K1: normalize rows -> packed bf16 ----------------
__global__ void __launch_bounds__(256) norm_bf16_kernel(const float* __restrict__ e,
                                                        unsigned int* __restrict__ en_packed) {
    const int row  = blockIdx.x * 4 + (threadIdx.x >> 6);
    const int lane = threadIdx.x & 63;
    const float2 v = *reinterpret_cast<const float2*>(e + row * DIM + lane * 2);
    float s = v.x * v.x + v.y * v.y;
    #pragma unroll
    for (int off = 32; off; off >>= 1) s += __shfl_xor(s, off, 64);
    const float scale = 1.0f / fmaxf(sqrtf(s), 1e-8f);
    const unsigned int lo = f2bf(v.x * scale);
    const unsigned int hi = f2bf(v.y * scale);
    en_packed[row * (DIM / 2) + lane] = (hi << 16) | lo;
}

// ---------------- fused real kernel: GEMM blocks (<Tc) + corr blocks ----------------
__global__ void __launch_bounds__(512, 4)
fused_kernel(const short* __restrict__ en, const int* __restrict__ labels, int n,
             float* __restrict__ partials, int nt, int Tc) {
    __shared__ __align__(16) short buf[2][64 * DIM];   // 32 KB (corr reuses as 128x128 tile)
    __shared__ float wsum[8];
    __shared__ int list[CAP];
    __shared__ int ccnt;

    const int tid  = threadIdx.x;
    const int lane = tid & 63;
    const int wid  = tid >> 6;

    if ((int)blockIdx.x >= Tc) {
        // ================= corr block: class c =================
        const int c = (int)blockIdx.x - Tc;
        if (tid == 0) ccnt = 0;
        __syncthreads();
        #pragma unroll 1
        for (int it = 0; it < n / 512; ++it) {      // 16 independent coalesced iters
            const int i = it * 512 + tid;
            if (labels[i] == c) {
                const int p = atomicAdd(&ccnt, 1);
                if (p < CAP) list[p] = i;
            }
        }
        __syncthreads();
        const int nc = min(ccnt, CAP);

        short* tile = &buf[0][0];                   // 128 rows x 128 cols
        if (nc > 1) {
            const int rlo = tid >> 4, sl = tid & 15;
            #pragma unroll
            for (int p = 0; p < 4; ++p) {
                const int r    = p * 32 + rlo;
                const int srow = list[r < nc ? r : 0];
                const int sc   = (sl ^ (r & 7)) << 4;
                load16_to_lds((const char*)en + (size_t)srow * 256 + sc,
                              (char*)tile + r * 256 + sl * 16);
            }
        }
        __syncthreads();

        float csum = 0.0f;
        if (nc > 1 && wid < 4) {
            const int wr = wid >> 1, wc = wid & 1;
            const int lm = lane & 15, hi = lane >> 4, rb = hi * 4;
            short8 a[4][4];
            #pragma unroll
            for (int m = 0; m < 4; ++m)
                #pragma unroll
                for (int ks = 0; ks < 4; ++ks)
                    a[m][ks] = read_frag(tile, wr * 64 + m * 16 + lm, hi + ks * 4);
            f32x4 acc[4][4] = {};
            #pragma unroll
            for (int ks = 0; ks < 4; ++ks) {
                short8 b[4];
                #pragma unroll
                for (int nn = 0; nn < 4; ++nn)
                    b[nn] = read_frag(tile, wc * 64 + nn * 16 + lm, hi + ks * 4);
                #pragma unroll
                for (int m = 0; m < 4; ++m)
                    #pragma unroll
                    for (int nn = 0; nn < 4; ++nn)
                        acc[m][nn] = __builtin_amdgcn_mfma_f32_16x16x32_bf16(a[m][ks], b[nn], acc[m][nn], 0, 0, 0);
            }
            #pragma unroll
            for (int m = 0; m < 4; ++m)
                #pragma unroll
                for (int nn = 0; nn < 4; ++nn) {
                    const int v = wc * 64 + nn * 16 + lm;
                    #pragma unroll
                    for (int r = 0; r < 4; ++r) {
                        const int u = wr * 64 + m * 16 + rb + r;
                        const float s = acc[m][nn][r];
                        const float t = (1.0f - s) - fmaxf(s - MARGIN, 0.0f);
                        csum += (u < v && v < nc) ? t : 0.0f;
                    }
                }
        }
        #pragma unroll
        for (int o = 32; o; o >>= 1) csum += __shfl_down(csum, o, 64);
        if (lane == 0) wsum[wid] = csum;
        __syncthreads();
        if (tid == 0) {
            float b = 0.0f;
            #pragma unroll
            for (int w = 0; w < 8; ++w) b += wsum[w];
            partials[blockIdx.x] = b;
        }
        return;
    }

    // ================= GEMM block =================
    int t  = blockIdx.x;
    int bi = 0, cnt = (nt + CHUNK - 1) / CHUNK;
    #pragma unroll 1
    while (t >= cnt) { t -= cnt; ++bi; cnt = (nt - bi + CHUNK - 1) / CHUNK; }
    const int jbase = bi + t * CHUNK;
    const int jb128 = jbase * 128;
    const int nsub  = 2 * min(CHUNK, nt - jbase);

    const int wr = wid >> 1;            // 0..3: 32-row band
    const int wc = wid & 1;             // 0..1: 32-col half
    const int lm = lane & 15;
    const int hi = lane >> 4;
    const int rb = hi * 4;

    stage64(en, bi * 128,      &buf[0][0], tid);
    stage64(en, bi * 128 + 64, &buf[1][0], tid);
    const int r0w = bi * 128 + wr * 32;
    __syncthreads();

    short8 a[2][4];
    const short* Abuf = &buf[wr >> 1][0];
    const int rloc = (wr & 1) * 32;
    #pragma unroll
    for (int m = 0; m < 2; ++m)
        #pragma unroll
        for (int ks = 0; ks < 4; ++ks)
            a[m][ks] = read_frag(Abuf, rloc + m * 16 + lm, hi + ks * 4);
    __syncthreads();

    stage64(en, jb128, &buf[0][0], tid);
    __syncthreads();

    f32x4 vsum = (f32x4){0.0f, 0.0f, 0.0f, 0.0f};
    #pragma unroll 1
    for (int s = 0; s < nsub; ++s) {
        const short* cur = &buf[s & 1][0];
        if (s + 1 < nsub)
            stage64(en, jb128 + (s + 1) * 64, &buf[(s + 1) & 1][0], tid);

        f32x4 acc[2][2] = {};
        #pragma unroll
        for (int ks = 0; ks < 4; ++ks) {
            short8 b[2];
            b[0] = read_frag(cur, wc * 32 + lm,      hi + ks * 4);
            b[1] = read_frag(cur, wc * 32 + 16 + lm, hi + ks * 4);
            #pragma unroll
            for (int m = 0; m < 2; ++m)
                #pragma unroll
                for (int n = 0; n < 2; ++n)
                    acc[m][n] = __builtin_amdgcn_mfma_f32_16x16x32_bf16(a[m][ks], b[n], acc[m][n], 0, 0, 0);
        }

        if ((jbase == bi) && (s < 2)) {
            const int c0 = jb128 + s * 64 + wc * 32;
            #pragma unroll
            for (int m = 0; m < 2; ++m)
                #pragma unroll
                for (int n = 0; n < 2; ++n) {
                    const f32x4 sv = acc[m][n] - MARGIN;
                    const int jj = c0 + n * 16 + lm;
                    #pragma unroll
                    for (int r = 0; r < 4; ++r) {
                        const int ii = r0w + m * 16 + rb + r;
                        vsum[r] += (ii < jj) ? fmaxf(sv[r], 0.0f) : 0.0f;
                    }
                }
        } else {
            #pragma unroll
            for (int m = 0; m < 2; ++m)
                #pragma unroll
                for (int n = 0; n < 2; ++n) {
                    const f32x4 sv = acc[m][n] - MARGIN;
                    #pragma unroll
                    for (int r = 0; r < 4; ++r)
                        vsum[r] += fmaxf(sv[r], 0.0f);
                }
        }
        __syncthreads();
    }

    float lsum = vsum[0] + vsum[1] + vsum[2] + vsum[3];
    #pragma unroll
    for (int off = 32; off; off >>= 1) lsum += __shfl_down(lsum, off, 64);
    if (lane == 0) wsum[wid] = lsum;
    __syncthreads();
    if (tid == 0) {
        float b = 0.0f;
        #pragma unroll
        for (int w = 0; w < 8; ++w) b += wsum[w];
        partials[blockIdx.x] = b;
    }
}

// ---------------- ablation template (scratch-only) ----------------
// V=1 full | V=2 acc-read-only | V=3 one-read/frag | V=4 no-barrier | V=5 no-stage
template<int V>
__global__ void __launch_bounds__(512, 4)
tri_abl(const short* __restrict__ en, float* __restrict__ outp, int nt, int reps) {
    __shared__ __align__(16) short buf[2][64 * DIM];
    __shared__ float wsum[8];

    int t  = blockIdx.x;
    int bi = 0, cnt = (nt + CHUNK - 1) / CHUNK;
    #pragma unroll 1
    while (t >= cnt) { t -= cnt; ++bi; cnt = (nt - bi + CHUNK - 1) / CHUNK; }
    const int jbase = bi + t * CHUNK;
    const int jb128 = jbase * 128;
    const int nsub  = 2 * min(CHUNK, nt - jbase);

    const int tid  = threadIdx.x;
    const int lane = tid & 63;
    const int wid  = tid >> 6;
    const int wr   = wid >> 1, wc = wid & 1;
    const int lm   = lane & 15, hi = lane >> 4, rb = hi * 4;

    stage64(en, bi * 128,      &buf[0][0], tid);
    stage64(en, bi * 128 + 64, &buf[1][0], tid);
    const int r0w = bi * 128 + wr * 32;
    __syncthreads();

    short8 a[2][4];
    const short* Abuf = &buf[wr >> 1][0];
    const int rloc = (wr & 1) * 32;
    #pragma unroll
    for (int m = 0; m < 2; ++m)
        #pragma unroll
        for (int ks = 0; ks < 4; ++ks)
            a[m][ks] = read_frag(Abuf, rloc + m * 16 + lm, hi + ks * 4);
    __syncthreads();

    stage64(en, jb128, &buf[0][0], tid);
    if (V == 5) stage64(en, jb128 + 64, &buf[1][0], tid);
    __syncthreads();

    f32x4 vsum = (f32x4){0.0f, 0.0f, 0.0f, 0.0f};
    #pragma unroll 1
    for (int rep = 0; rep < reps; ++rep) {
        #pragma unroll 1
        for (int s = 0; s < nsub; ++s) {
            const short* cur = &buf[s & 1][0];
            if (V != 5)
                stage64(en, jb128 + ((s + 1) % nsub) * 64, &buf[(s + 1) & 1][0], tid);

            f32x4 acc[2][2] = {};
            #pragma unroll
            for (int ks = 0; ks < 4; ++ks) {
                short8 b[2];
                b[0] = read_frag(cur, wc * 32 + lm,      hi + ks * 4);
                b[1] = read_frag(cur, wc * 32 + 16 + lm, hi + ks * 4);
                #pragma unroll
                for (int m = 0; m < 2; ++m)
                    #pragma unroll
                    for (int n = 0; n < 2; ++n)
                        acc[m][n] = __builtin_amdgcn_mfma_f32_16x16x32_bf16(a[m][ks], b[n], acc[m][n], 0, 0, 0);
            }

            if (V == 2) {                 // acc readout + add only
                #pragma unroll
                for (int m = 0; m < 2; ++m)
                    #pragma unroll
                    for (int n = 0; n < 2; ++n)
                        #pragma unroll
                        for (int r = 0; r < 4; ++r)
                            vsum[r] += acc[m][n][r];
            } else if (V == 3) {          // one read per fragment
                #pragma unroll
                for (int m = 0; m < 2; ++m)
                    #pragma unroll
                    for (int n = 0; n < 2; ++n)
                        vsum[0] += acc[m][n][0];
            } else {                      // V1/V4/V5: full label-blind epilogue
                if ((jbase == bi) && (s < 2)) {
                    const int c0 = jb128 + s * 64 + wc * 32;
                    #pragma unroll
                    for (int m = 0; m < 2; ++m)
                        #pragma unroll
                        for (int n = 0; n < 2; ++n) {
                            const f32x4 sv = acc[m][n] - MARGIN;
                            const int jj = c0 + n * 16 + lm;
                            #pragma unroll
                            for (int r = 0; r < 4; ++r) {
                                const int ii = r0w + m * 16 + rb + r;
                                vsum[r] += (ii < jj) ? fmaxf(sv[r], 0.0f) : 0.0f;
                            }
                        }
                } else {
                    #pragma unroll
                    for (int m = 0; m < 2; ++m)
                        #pragma unroll
                        for (int n = 0; n < 2; ++n) {
                            const f32x4 sv = acc[m][n] - MARGIN;
                            #pragma unroll
                            for (int r = 0; r < 4; ++r)
                                vsum[r] += fmaxf(sv[r], 0.0f);
                        }
                }
            }
            if (V != 4) __syncthreads();
        }
    }

    float lsum = vsum[0] + vsum[1] + vsum[2] + vsum[3];
    #pragma unroll
    for (int off = 32; off; off >>= 1) lsum += __shfl_down(lsum, off, 64);
    if (lane == 0) wsum[wid] = lsum;
    __syncthreads();
    if (tid == 0) {
        float b = 0.0f;
        #pragma unroll
        for (int w = 0; w < 8; ++w) b += wsum[w];
        outp[blockIdx.x] = b;
    }
}

// ---------------- K3: final deterministic reduce ----------------
__global__ void __launch_bounds__(256) final_reduce_kernel(const float* __restrict__ partials,
                                                           float* __restrict__ out,
                                                           int n, float inv_denom) {
    float s = 0.0f;
    for (int i = threadIdx.x; i < n; i += 256) s += partials[i];
    #pragma unroll
    for (int off = 32; off; off >>= 1) s += __shfl_xor(s, off, 64);
    __shared__ float wsum[4];
    if ((threadIdx.x & 63) == 0) wsum[threadIdx.x >> 6] = s;
    __syncthreads();
    if (threadIdx.x == 0) out[0] = (wsum[0] + wsum[1] + wsum[2] + wsum[3]) * inv_denom;
}

extern "C" void kernel_launch(void* const* d_in, const int* in_sizes, int n_in,
                              void* d_out, int out_size, void* d_ws, size_t ws_size,
                              hipStream_t stream) {
    const float* emb    = (const float*)d_in[0];
    const int*   labels = (const int*)d_in[1];
    float*       out    = (float*)d_out;

    const int n  = in_sizes[1];      // 8192
    const int nt = n / 128;          // 64 strips

    int Tc = 0;                      // 544 GEMM blocks at CHUNK=4
    for (int i = 0; i < nt; ++i) Tc += (nt - i + CHUNK - 1) / CHUNK;

    unsigned int* en_packed = (unsigned int*)d_ws;
    short*        en        = (short*)d_ws;
    float*        partials  = (float*)((char*)d_ws + (size_t)n * DIM * 2);  // Tc+NLAB
    float*        scratch   = partials + Tc + NLAB;                          // Tc floats

    norm_bf16_kernel<<<n / 4, 256, 0, stream>>>(emb, en_packed);

    fused_kernel<<<Tc + NLAB, 512, 0, stream>>>(en, labels, n, partials, nt, Tc);

    const float inv_denom = (float)(1.0 / ((double)n * (double)(n - 1)));
    final_reduce_kernel<<<1, 256, 0, stream>>>(partials, out, Tc + NLAB, inv_denom);

    // ---- ablations (scratch-only, sized to surface above the ~40us fills) ----
    tri_abl<1><<<Tc, 512, 0, stream>>>(en, scratch, nt, 4);
    tri_abl<2><<<Tc, 512, 0, stream>>>(en, scratch, nt, 8);
    tri_abl<3><<<Tc, 512, 0, stream>>>(en, scratch, nt, 8);
    tri_abl<4><<<Tc, 512, 0, stream>>>(en, scratch, nt, 4);
    tri_abl<5><<<Tc, 512, 0, stream>>>(en, scratch, nt, 4);
}

// Round 18
// 30.008 us; speedup vs baseline: 10.5798x; 10.5798x over previous
//
#include <hip/hip_runtime.h>
#include <hip/hip_bf16.h>

// PseudoTripletLoss on MI355X (gfx950)
// loss*n(n-1) = sum_{i<j} relu(s-0.1)                 [GEMM blocks, label-blind]
//             + sum_{i<j,same} ((1-s) - relu(s-0.1))  [corr blocks, same dispatch, FIRST]
// R18: corr blocks lead the grid (overlap, not tail); GEMM prologue reduced to
// ONE barrier drain via a dedicated A LDS buffer (no bounce through B buffers).
// Subtile loop identical to the structure measured at 10.2 us/pass in R17.

typedef __attribute__((ext_vector_type(8))) short short8;
typedef __attribute__((ext_vector_type(4))) float f32x4;

#define DIM 128
#define MARGIN 0.1f
#define CHUNK 4
#define NLAB 100
#define CAP 128

typedef const void __attribute__((address_space(1)))* gas_ptr;
typedef void __attribute__((address_space(3)))* las_ptr;

static __device__ __forceinline__ void load16_to_lds(const void* g, void* l) {
    __builtin_amdgcn_global_load_lds((gas_ptr)g, (las_ptr)l, 16, 0, 0);
}

static __device__ __forceinline__ unsigned short f2bf(float f) {
    unsigned int u = __builtin_bit_cast(unsigned int, f);
    u += 0x7FFFu + ((u >> 16) & 1u);
    return (unsigned short)(u >> 16);
}

// 512-thread staging of a 64x128 bf16 tile; lane-linear LDS dest; XOR
// involution on the SOURCE column.
static __device__ __forceinline__ void stage64(const short* __restrict__ en, int row0,
                                               short* buf, int tid) {
    const char* src = (const char*)(en + (size_t)row0 * DIM);
    char* dst = (char*)buf;
    const int r_lo = tid >> 4;
    const int s    = tid & 15;
    #pragma unroll
    for (int p = 0; p < 2; ++p) {
        const int r  = p * 32 + r_lo;
        const int sc = (s ^ (r & 7)) << 4;
        load16_to_lds(src + (size_t)r * 256 + sc, dst + r * 256 + s * 16);
    }
}

static __device__ __forceinline__ short8 read_frag(const short* buf, int row, int slot) {
    const int ps = slot ^ (row & 7);
    return *(const short8*)(buf + row * DIM + ps * 8);
}

// ---------------- K1: normalize rows -> packed bf16 ----------------
__global__ void __launch_bounds__(256) norm_bf16_kernel(const float* __restrict__ e,
                                                        unsigned int* __restrict__ en_packed) {
    const int row  = blockIdx.x * 4 + (threadIdx.x >> 6);
    const int lane = threadIdx.x & 63;
    const float2 v = *reinterpret_cast<const float2*>(e + row * DIM + lane * 2);
    float s = v.x * v.x + v.y * v.y;
    #pragma unroll
    for (int off = 32; off; off >>= 1) s += __shfl_xor(s, off, 64);
    const float scale = 1.0f / fmaxf(sqrtf(s), 1e-8f);
    const unsigned int lo = f2bf(v.x * scale);
    const unsigned int hi = f2bf(v.y * scale);
    en_packed[row * (DIM / 2) + lane] = (hi << 16) | lo;
}

// ---------------- fused kernel: corr blocks (< NLAB) then GEMM blocks ----------------
__global__ void __launch_bounds__(512, 2)
fused_kernel(const short* __restrict__ en, const int* __restrict__ labels, int n,
             float* __restrict__ partials, int nt) {
    __shared__ __align__(16) short Abuf[128 * DIM];    // 32 KB (A strip / corr tile)
    __shared__ __align__(16) short buf[2][64 * DIM];   // 32 KB (B double buffer)
    __shared__ float wsum[8];
    __shared__ int list[CAP];
    __shared__ int ccnt;

    const int tid  = threadIdx.x;
    const int lane = tid & 63;
    const int wid  = tid >> 6;
    const int lm   = lane & 15;
    const int hi   = lane >> 4;
    const int rb   = hi * 4;

    if ((int)blockIdx.x < NLAB) {
        // ================= corr block: class c (runs FIRST, overlaps GEMM) =================
        const int c = (int)blockIdx.x;
        if (tid == 0) ccnt = 0;
        __syncthreads();
        #pragma unroll 1
        for (int it = 0; it < n / 512; ++it) {       // 16 coalesced iterations
            const int i = it * 512 + tid;
            if (labels[i] == c) {
                const int p = atomicAdd(&ccnt, 1);   // order-free: pair set is invariant
                if (p < CAP) list[p] = i;
            }
        }
        __syncthreads();
        const int nc = min(ccnt, CAP);

        float csum = 0.0f;
        if (nc > 1) {
            // gather class rows into Abuf (128 rows x 128 cols)
            {
                const int rlo = tid >> 4, sl = tid & 15;
                #pragma unroll
                for (int p = 0; p < 4; ++p) {
                    const int r    = p * 32 + rlo;
                    const int srow = list[r < nc ? r : 0];
                    const int sc   = (sl ^ (r & 7)) << 4;
                    load16_to_lds((const char*)en + (size_t)srow * 256 + sc,
                                  (char*)Abuf + r * 256 + sl * 16);
                }
            }
            __syncthreads();

            // 8 waves: wave tile = 32 rows x 64 cols of the 128x128 sim tile
            const int wr = wid >> 1;      // 0..3
            const int wc = wid & 1;       // 0..1
            short8 a[2][4];
            #pragma unroll
            for (int m = 0; m < 2; ++m)
                #pragma unroll
                for (int ks = 0; ks < 4; ++ks)
                    a[m][ks] = read_frag(Abuf, wr * 32 + m * 16 + lm, hi + ks * 4);

            f32x4 acc[2][4] = {};
            #pragma unroll
            for (int ks = 0; ks < 4; ++ks) {
                short8 b[4];
                #pragma unroll
                for (int nn = 0; nn < 4; ++nn)
                    b[nn] = read_frag(Abuf, wc * 64 + nn * 16 + lm, hi + ks * 4);
                #pragma unroll
                for (int m = 0; m < 2; ++m)
                    #pragma unroll
                    for (int nn = 0; nn < 4; ++nn)
                        acc[m][nn] = __builtin_amdgcn_mfma_f32_16x16x32_bf16(a[m][ks], b[nn], acc[m][nn], 0, 0, 0);
            }

            #pragma unroll
            for (int m = 0; m < 2; ++m)
                #pragma unroll
                for (int nn = 0; nn < 4; ++nn) {
                    const int v = wc * 64 + nn * 16 + lm;
                    #pragma unroll
                    for (int r = 0; r < 4; ++r) {
                        const int u = wr * 32 + m * 16 + rb + r;
                        const float s = acc[m][nn][r];
                        const float t = (1.0f - s) - fmaxf(s - MARGIN, 0.0f);
                        csum += (u < v && v < nc) ? t : 0.0f;
                    }
                }
        } else {
            __syncthreads();   // keep barrier count uniform (all threads reach)
        }

        #pragma unroll
        for (int o = 32; o; o >>= 1) csum += __shfl_down(csum, o, 64);
        if (lane == 0) wsum[wid] = csum;
        __syncthreads();
        if (tid == 0) {
            float b = 0.0f;
            #pragma unroll
            for (int w = 0; w < 8; ++w) b += wsum[w];
            partials[blockIdx.x] = b;
        }
        return;
    }

    // ================= GEMM block (label-blind) =================
    int t  = (int)blockIdx.x - NLAB;
    int bi = 0, cnt = (nt + CHUNK - 1) / CHUNK;
    #pragma unroll 1
    while (t >= cnt) { t -= cnt; ++bi; cnt = (nt - bi + CHUNK - 1) / CHUNK; }
    const int jbase = bi + t * CHUNK;
    const int jb128 = jbase * 128;
    const int nsub  = 2 * min(CHUNK, nt - jbase);

    const int wr = wid >> 1;            // 0..3: 32-row band
    const int wc = wid & 1;             // 0..1: 32-col half

    // ---- single-drain prologue: A strip + B0 staged together ----
    stage64(en, bi * 128,      Abuf,            tid);
    stage64(en, bi * 128 + 64, Abuf + 64 * DIM, tid);
    stage64(en, jb128,         &buf[0][0],      tid);
    const int r0w = bi * 128 + wr * 32;
    __syncthreads();                    // ONE drain: A + B0 ready

    short8 a[2][4];
    #pragma unroll
    for (int m = 0; m < 2; ++m)
        #pragma unroll
        for (int ks = 0; ks < 4; ++ks)
            a[m][ks] = read_frag(Abuf, wr * 32 + m * 16 + lm, hi + ks * 4);

    f32x4 vsum = (f32x4){0.0f, 0.0f, 0.0f, 0.0f};
    #pragma unroll 1
    for (int s = 0; s < nsub; ++s) {
        const short* cur = &buf[s & 1][0];
        if (s + 1 < nsub)
            stage64(en, jb128 + (s + 1) * 64, &buf[(s + 1) & 1][0], tid);

        f32x4 acc[2][2] = {};
        #pragma unroll
        for (int ks = 0; ks < 4; ++ks) {
            short8 b[2];
            b[0] = read_frag(cur, wc * 32 + lm,      hi + ks * 4);
            b[1] = read_frag(cur, wc * 32 + 16 + lm, hi + ks * 4);
            #pragma unroll
            for (int m = 0; m < 2; ++m)
                #pragma unroll
                for (int n = 0; n < 2; ++n)
                    acc[m][n] = __builtin_amdgcn_mfma_f32_16x16x32_bf16(a[m][ks], b[n], acc[m][n], 0, 0, 0);
        }

        // label-blind epilogue: 3 ops/elem
        if ((jbase == bi) && (s < 2)) {            // diagonal subtile: strict i<j
            const int c0 = jb128 + s * 64 + wc * 32;
            #pragma unroll
            for (int m = 0; m < 2; ++m)
                #pragma unroll
                for (int n = 0; n < 2; ++n) {
                    const f32x4 sv = acc[m][n] - MARGIN;
                    const int jj = c0 + n * 16 + lm;
                    #pragma unroll
                    for (int r = 0; r < 4; ++r) {
                        const int ii = r0w + m * 16 + rb + r;
                        vsum[r] += (ii < jj) ? fmaxf(sv[r], 0.0f) : 0.0f;
                    }
                }
        } else {
            #pragma unroll
            for (int m = 0; m < 2; ++m)
                #pragma unroll
                for (int n = 0; n < 2; ++n) {
                    const f32x4 sv = acc[m][n] - MARGIN;
                    #pragma unroll
                    for (int r = 0; r < 4; ++r)
                        vsum[r] += fmaxf(sv[r], 0.0f);
                }
        }
        __syncthreads();   // drains stage(s+1) + all reads of buf[s&1]
    }

    float lsum = vsum[0] + vsum[1] + vsum[2] + vsum[3];
    #pragma unroll
    for (int off = 32; off; off >>= 1) lsum += __shfl_down(lsum, off, 64);
    if (lane == 0) wsum[wid] = lsum;
    __syncthreads();
    if (tid == 0) {
        float b = 0.0f;
        #pragma unroll
        for (int w = 0; w < 8; ++w) b += wsum[w];
        partials[blockIdx.x] = b;
    }
}

// ---------------- K3: final deterministic reduce ----------------
__global__ void __launch_bounds__(256) final_reduce_kernel(const float* __restrict__ partials,
                                                           float* __restrict__ out,
                                                           int n, float inv_denom) {
    float s = 0.0f;
    for (int i = threadIdx.x; i < n; i += 256) s += partials[i];
    #pragma unroll
    for (int off = 32; off; off >>= 1) s += __shfl_xor(s, off, 64);
    __shared__ float wsum[4];
    if ((threadIdx.x & 63) == 0) wsum[threadIdx.x >> 6] = s;
    __syncthreads();
    if (threadIdx.x == 0) out[0] = (wsum[0] + wsum[1] + wsum[2] + wsum[3]) * inv_denom;
}

extern "C" void kernel_launch(void* const* d_in, const int* in_sizes, int n_in,
                              void* d_out, int out_size, void* d_ws, size_t ws_size,
                              hipStream_t stream) {
    const float* emb    = (const float*)d_in[0];
    const int*   labels = (const int*)d_in[1];
    float*       out    = (float*)d_out;

    const int n  = in_sizes[1];      // 8192
    const int nt = n / 128;          // 64 strips

    int Tc = 0;                      // 544 GEMM blocks at CHUNK=4
    for (int i = 0; i < nt; ++i) Tc += (nt - i + CHUNK - 1) / CHUNK;

    unsigned int* en_packed = (unsigned int*)d_ws;
    short*        en        = (short*)d_ws;
    float*        partials  = (float*)((char*)d_ws + (size_t)n * DIM * 2);  // NLAB+Tc

    norm_bf16_kernel<<<n / 4, 256, 0, stream>>>(emb, en_packed);

    fused_kernel<<<NLAB + Tc, 512, 0, stream>>>(en, labels, n, partials, nt);

    const float inv_denom = (float)(1.0 / ((double)n * (double)(n - 1)));
    final_reduce_kernel<<<1, 256, 0, stream>>>(partials, out, NLAB + Tc, inv_denom);
}

// Round 19
// 29.568 us; speedup vs baseline: 10.7374x; 1.0149x over previous
//
#include <hip/hip_runtime.h>
#include <hip/hip_bf16.h>

// PseudoTripletLoss on MI355X (gfx950)
// loss*n(n-1) = sum_{i<j} relu(s-0.1)                 [GEMM blocks, label-blind]
//             + sum_{i<j,same} ((1-s) - relu(s-0.1))  [corr blocks, same dispatch, FIRST]
// R19: R18 structure + two cold-path fixes:
//  (1) norm writes en via __builtin_nontemporal_store -> no dirty lines stuck
//      in the writer XCD's L2 (GEMM reads were cross-XCD snoops = the ~14us).
//  (2) XCD-bijective swizzle of GEMM block ids (544 = 8*68) -> contiguous
//      strip bands per XCD -> A/B re-reads stay in local L2.

typedef __attribute__((ext_vector_type(8))) short short8;
typedef __attribute__((ext_vector_type(4))) float f32x4;

#define DIM 128
#define MARGIN 0.1f
#define CHUNK 4
#define NLAB 100
#define CAP 128

typedef const void __attribute__((address_space(1)))* gas_ptr;
typedef void __attribute__((address_space(3)))* las_ptr;

static __device__ __forceinline__ void load16_to_lds(const void* g, void* l) {
    __builtin_amdgcn_global_load_lds((gas_ptr)g, (las_ptr)l, 16, 0, 0);
}

static __device__ __forceinline__ unsigned short f2bf(float f) {
    unsigned int u = __builtin_bit_cast(unsigned int, f);
    u += 0x7FFFu + ((u >> 16) & 1u);
    return (unsigned short)(u >> 16);
}

// 512-thread staging of a 64x128 bf16 tile; lane-linear LDS dest; XOR
// involution on the SOURCE column.
static __device__ __forceinline__ void stage64(const short* __restrict__ en, int row0,
                                               short* buf, int tid) {
    const char* src = (const char*)(en + (size_t)row0 * DIM);
    char* dst = (char*)buf;
    const int r_lo = tid >> 4;
    const int s    = tid & 15;
    #pragma unroll
    for (int p = 0; p < 2; ++p) {
        const int r  = p * 32 + r_lo;
        const int sc = (s ^ (r & 7)) << 4;
        load16_to_lds(src + (size_t)r * 256 + sc, dst + r * 256 + s * 16);
    }
}

static __device__ __forceinline__ short8 read_frag(const short* buf, int row, int slot) {
    const int ps = slot ^ (row & 7);
    return *(const short8*)(buf + row * DIM + ps * 8);
}

// ---------------- K1: normalize rows -> packed bf16 (non-temporal stores) ----------------
__global__ void __launch_bounds__(256) norm_bf16_kernel(const float* __restrict__ e,
                                                        unsigned int* __restrict__ en_packed) {
    const int row  = blockIdx.x * 4 + (threadIdx.x >> 6);
    const int lane = threadIdx.x & 63;
    const float2 v = *reinterpret_cast<const float2*>(e + row * DIM + lane * 2);
    float s = v.x * v.x + v.y * v.y;
    #pragma unroll
    for (int off = 32; off; off >>= 1) s += __shfl_xor(s, off, 64);
    const float scale = 1.0f / fmaxf(sqrtf(s), 1e-8f);
    const unsigned int lo = f2bf(v.x * scale);
    const unsigned int hi = f2bf(v.y * scale);
    __builtin_nontemporal_store((hi << 16) | lo, &en_packed[row * (DIM / 2) + lane]);
}

// ---------------- fused kernel: corr blocks (< NLAB) then swizzled GEMM blocks ----------------
__global__ void __launch_bounds__(512, 2)
fused_kernel(const short* __restrict__ en, const int* __restrict__ labels, int n,
             float* __restrict__ partials, int nt) {
    __shared__ __align__(16) short Abuf[128 * DIM];    // 32 KB (A strip / corr tile)
    __shared__ __align__(16) short buf[2][64 * DIM];   // 32 KB (B double buffer)
    __shared__ float wsum[8];
    __shared__ int list[CAP];
    __shared__ int ccnt;

    const int tid  = threadIdx.x;
    const int lane = tid & 63;
    const int wid  = tid >> 6;
    const int lm   = lane & 15;
    const int hi   = lane >> 4;
    const int rb   = hi * 4;

    if ((int)blockIdx.x < NLAB) {
        // ================= corr block: class c (runs FIRST, overlaps GEMM) =================
        const int c = (int)blockIdx.x;
        if (tid == 0) ccnt = 0;
        __syncthreads();
        #pragma unroll 1
        for (int it = 0; it < n / 512; ++it) {       // 16 coalesced iterations
            const int i = it * 512 + tid;
            if (labels[i] == c) {
                const int p = atomicAdd(&ccnt, 1);   // order-free: pair set invariant
                if (p < CAP) list[p] = i;
            }
        }
        __syncthreads();
        const int nc = min(ccnt, CAP);

        float csum = 0.0f;
        if (nc > 1) {
            {
                const int rlo = tid >> 4, sl = tid & 15;
                #pragma unroll
                for (int p = 0; p < 4; ++p) {
                    const int r    = p * 32 + rlo;
                    const int srow = list[r < nc ? r : 0];
                    const int sc   = (sl ^ (r & 7)) << 4;
                    load16_to_lds((const char*)en + (size_t)srow * 256 + sc,
                                  (char*)Abuf + r * 256 + sl * 16);
                }
            }
            __syncthreads();

            const int wr = wid >> 1;      // 0..3
            const int wc = wid & 1;       // 0..1
            short8 a[2][4];
            #pragma unroll
            for (int m = 0; m < 2; ++m)
                #pragma unroll
                for (int ks = 0; ks < 4; ++ks)
                    a[m][ks] = read_frag(Abuf, wr * 32 + m * 16 + lm, hi + ks * 4);

            f32x4 acc[2][4] = {};
            #pragma unroll
            for (int ks = 0; ks < 4; ++ks) {
                short8 b[4];
                #pragma unroll
                for (int nn = 0; nn < 4; ++nn)
                    b[nn] = read_frag(Abuf, wc * 64 + nn * 16 + lm, hi + ks * 4);
                #pragma unroll
                for (int m = 0; m < 2; ++m)
                    #pragma unroll
                    for (int nn = 0; nn < 4; ++nn)
                        acc[m][nn] = __builtin_amdgcn_mfma_f32_16x16x32_bf16(a[m][ks], b[nn], acc[m][nn], 0, 0, 0);
            }

            #pragma unroll
            for (int m = 0; m < 2; ++m)
                #pragma unroll
                for (int nn = 0; nn < 4; ++nn) {
                    const int v = wc * 64 + nn * 16 + lm;
                    #pragma unroll
                    for (int r = 0; r < 4; ++r) {
                        const int u = wr * 32 + m * 16 + rb + r;
                        const float s = acc[m][nn][r];
                        const float t = (1.0f - s) - fmaxf(s - MARGIN, 0.0f);
                        csum += (u < v && v < nc) ? t : 0.0f;
                    }
                }
        } else {
            __syncthreads();   // uniform barrier count
        }

        #pragma unroll
        for (int o = 32; o; o >>= 1) csum += __shfl_down(csum, o, 64);
        if (lane == 0) wsum[wid] = csum;
        __syncthreads();
        if (tid == 0) {
            float b = 0.0f;
            #pragma unroll
            for (int w = 0; w < 8; ++w) b += wsum[w];
            partials[blockIdx.x] = b;
        }
        return;
    }

    // ================= GEMM block (label-blind), XCD-bijective swizzle =================
    {
        const int graw = (int)blockIdx.x - NLAB;     // 0..543 ; 544 = 8*68
        int t = (graw & 7) * 68 + (graw >> 3);       // same-XCD -> contiguous band
        int bi = 0, cnt = (nt + CHUNK - 1) / CHUNK;
        #pragma unroll 1
        while (t >= cnt) { t -= cnt; ++bi; cnt = (nt - bi + CHUNK - 1) / CHUNK; }
        const int jbase = bi + t * CHUNK;
        const int jb128 = jbase * 128;
        const int nsub  = 2 * min(CHUNK, nt - jbase);

        const int wr = wid >> 1;            // 0..3: 32-row band
        const int wc = wid & 1;             // 0..1: 32-col half

        // single-drain prologue: A strip + B0 staged together
        stage64(en, bi * 128,      Abuf,            tid);
        stage64(en, bi * 128 + 64, Abuf + 64 * DIM, tid);
        stage64(en, jb128,         &buf[0][0],      tid);
        const int r0w = bi * 128 + wr * 32;
        __syncthreads();                    // ONE drain: A + B0 ready

        short8 a[2][4];
        #pragma unroll
        for (int m = 0; m < 2; ++m)
            #pragma unroll
            for (int ks = 0; ks < 4; ++ks)
                a[m][ks] = read_frag(Abuf, wr * 32 + m * 16 + lm, hi + ks * 4);

        f32x4 vsum = (f32x4){0.0f, 0.0f, 0.0f, 0.0f};
        #pragma unroll 1
        for (int s = 0; s < nsub; ++s) {
            const short* cur = &buf[s & 1][0];
            if (s + 1 < nsub)
                stage64(en, jb128 + (s + 1) * 64, &buf[(s + 1) & 1][0], tid);

            f32x4 acc[2][2] = {};
            #pragma unroll
            for (int ks = 0; ks < 4; ++ks) {
                short8 b[2];
                b[0] = read_frag(cur, wc * 32 + lm,      hi + ks * 4);
                b[1] = read_frag(cur, wc * 32 + 16 + lm, hi + ks * 4);
                #pragma unroll
                for (int m = 0; m < 2; ++m)
                    #pragma unroll
                    for (int n = 0; n < 2; ++n)
                        acc[m][n] = __builtin_amdgcn_mfma_f32_16x16x32_bf16(a[m][ks], b[n], acc[m][n], 0, 0, 0);
            }

            if ((jbase == bi) && (s < 2)) {            // diagonal subtile: strict i<j
                const int c0 = jb128 + s * 64 + wc * 32;
                #pragma unroll
                for (int m = 0; m < 2; ++m)
                    #pragma unroll
                    for (int n = 0; n < 2; ++n) {
                        const f32x4 sv = acc[m][n] - MARGIN;
                        const int jj = c0 + n * 16 + lm;
                        #pragma unroll
                        for (int r = 0; r < 4; ++r) {
                            const int ii = r0w + m * 16 + rb + r;
                            vsum[r] += (ii < jj) ? fmaxf(sv[r], 0.0f) : 0.0f;
                        }
                    }
            } else {
                #pragma unroll
                for (int m = 0; m < 2; ++m)
                    #pragma unroll
                    for (int n = 0; n < 2; ++n) {
                        const f32x4 sv = acc[m][n] - MARGIN;
                        #pragma unroll
                        for (int r = 0; r < 4; ++r)
                            vsum[r] += fmaxf(sv[r], 0.0f);
                    }
            }
            __syncthreads();   // drains stage(s+1) + all reads of buf[s&1]
        }

        float lsum = vsum[0] + vsum[1] + vsum[2] + vsum[3];
        #pragma unroll
        for (int off = 32; off; off >>= 1) lsum += __shfl_down(lsum, off, 64);
        if (lane == 0) wsum[wid] = lsum;
        __syncthreads();
        if (tid == 0) {
            float b = 0.0f;
            #pragma unroll
            for (int w = 0; w < 8; ++w) b += wsum[w];
            partials[blockIdx.x] = b;
        }
    }
}

// ---------------- K3: final deterministic reduce ----------------
__global__ void __launch_bounds__(256) final_reduce_kernel(const float* __restrict__ partials,
                                                           float* __restrict__ out,
                                                           int n, float inv_denom) {
    float s = 0.0f;
    for (int i = threadIdx.x; i < n; i += 256) s += partials[i];
    #pragma unroll
    for (int off = 32; off; off >>= 1) s += __shfl_xor(s, off, 64);
    __shared__ float wsum[4];
    if ((threadIdx.x & 63) == 0) wsum[threadIdx.x >> 6] = s;
    __syncthreads();
    if (threadIdx.x == 0) out[0] = (wsum[0] + wsum[1] + wsum[2] + wsum[3]) * inv_denom;
}

extern "C" void kernel_launch(void* const* d_in, const int* in_sizes, int n_in,
                              void* d_out, int out_size, void* d_ws, size_t ws_size,
                              hipStream_t stream) {
    const float* emb    = (const float*)d_in[0];
    const int*   labels = (const int*)d_in[1];
    float*       out    = (float*)d_out;

    const int n  = in_sizes[1];      // 8192
    const int nt = n / 128;          // 64 strips

    int Tc = 0;                      // 544 GEMM blocks at CHUNK=4
    for (int i = 0; i < nt; ++i) Tc += (nt - i + CHUNK - 1) / CHUNK;

    unsigned int* en_packed = (unsigned int*)d_ws;
    short*        en        = (short*)d_ws;
    float*        partials  = (float*)((char*)d_ws + (size_t)n * DIM * 2);  // NLAB+Tc

    norm_bf16_kernel<<<n / 4, 256, 0, stream>>>(emb, en_packed);

    fused_kernel<<<NLAB + Tc, 512, 0, stream>>>(en, labels, n, partials, nt);

    const float inv_denom = (float)(1.0 / ((double)n * (double)(n - 1)));
    final_reduce_kernel<<<1, 256, 0, stream>>>(partials, out, NLAB + Tc, inv_denom);
}

// Round 20
// 29.121 us; speedup vs baseline: 10.9022x; 1.0153x over previous
//
#include <hip/hip_runtime.h>
#include <hip/hip_bf16.h>

// PseudoTripletLoss on MI355X (gfx950)
// loss*n(n-1) = sum_{i<j} relu(s-0.1)                 [GEMM blocks, label-blind]
//             + sum_{i<j,same} ((1-s) - relu(s-0.1))  [corr blocks, same dispatch, FIRST]
// R19: R18 structure + two cold-path fixes:
//  (1) norm writes en via __builtin_nontemporal_store -> no dirty lines stuck
//      in the writer XCD's L2 (GEMM reads were cross-XCD snoops = the ~14us).
//  (2) XCD-bijective swizzle of GEMM block ids (544 = 8*68) -> contiguous
//      strip bands per XCD -> A/B re-reads stay in local L2.

typedef __attribute__((ext_vector_type(8))) short short8;
typedef __attribute__((ext_vector_type(4))) float f32x4;

#define DIM 128
#define MARGIN 0.1f
#define CHUNK 4
#define NLAB 100
#define CAP 128

typedef const void __attribute__((address_space(1)))* gas_ptr;
typedef void __attribute__((address_space(3)))* las_ptr;

static __device__ __forceinline__ void load16_to_lds(const void* g, void* l) {
    __builtin_amdgcn_global_load_lds((gas_ptr)g, (las_ptr)l, 16, 0, 0);
}

static __device__ __forceinline__ unsigned short f2bf(float f) {
    unsigned int u = __builtin_bit_cast(unsigned int, f);
    u += 0x7FFFu + ((u >> 16) & 1u);
    return (unsigned short)(u >> 16);
}

// 512-thread staging of a 64x128 bf16 tile; lane-linear LDS dest; XOR
// involution on the SOURCE column.
static __device__ __forceinline__ void stage64(const short* __restrict__ en, int row0,
                                               short* buf, int tid) {
    const char* src = (const char*)(en + (size_t)row0 * DIM);
    char* dst = (char*)buf;
    const int r_lo = tid >> 4;
    const int s    = tid & 15;
    #pragma unroll
    for (int p = 0; p < 2; ++p) {
        const int r  = p * 32 + r_lo;
        const int sc = (s ^ (r & 7)) << 4;
        load16_to_lds(src + (size_t)r * 256 + sc, dst + r * 256 + s * 16);
    }
}

static __device__ __forceinline__ short8 read_frag(const short* buf, int row, int slot) {
    const int ps = slot ^ (row & 7);
    return *(const short8*)(buf + row * DIM + ps * 8);
}

// ---------------- K1: normalize rows -> packed bf16 (non-temporal stores) ----------------
__global__ void __launch_bounds__(256) norm_bf16_kernel(const float* __restrict__ e,
                                                        unsigned int* __restrict__ en_packed) {
    const int row  = blockIdx.x * 4 + (threadIdx.x >> 6);
    const int lane = threadIdx.x & 63;
    const float2 v = *reinterpret_cast<const float2*>(e + row * DIM + lane * 2);
    float s = v.x * v.x + v.y * v.y;
    #pragma unroll
    for (int off = 32; off; off >>= 1) s += __shfl_xor(s, off, 64);
    const float scale = 1.0f / fmaxf(sqrtf(s), 1e-8f);
    const unsigned int lo = f2bf(v.x * scale);
    const unsigned int hi = f2bf(v.y * scale);
    __builtin_nontemporal_store((hi << 16) | lo, &en_packed[row * (DIM / 2) + lane]);
}

// ---------------- fused kernel: corr blocks (< NLAB) then swizzled GEMM blocks ----------------
__global__ void __launch_bounds__(512, 2)
fused_kernel(const short* __restrict__ en, const int* __restrict__ labels, int n,
             float* __restrict__ partials, int nt) {
    __shared__ __align__(16) short Abuf[128 * DIM];    // 32 KB (A strip / corr tile)
    __shared__ __align__(16) short buf[2][64 * DIM];   // 32 KB (B double buffer)
    __shared__ float wsum[8];
    __shared__ int list[CAP];
    __shared__ int ccnt;

    const int tid  = threadIdx.x;
    const int lane = tid & 63;
    const int wid  = tid >> 6;
    const int lm   = lane & 15;
    const int hi   = lane >> 4;
    const int rb   = hi * 4;

    if ((int)blockIdx.x < NLAB) {
        // ================= corr block: class c (runs FIRST, overlaps GEMM) =================
        const int c = (int)blockIdx.x;
        if (tid == 0) ccnt = 0;
        __syncthreads();
        #pragma unroll 1
        for (int it = 0; it < n / 512; ++it) {       // 16 coalesced iterations
            const int i = it * 512 + tid;
            if (labels[i] == c) {
                const int p = atomicAdd(&ccnt, 1);   // order-free: pair set invariant
                if (p < CAP) list[p] = i;
            }
        }
        __syncthreads();
        const int nc = min(ccnt, CAP);

        float csum = 0.0f;
        if (nc > 1) {
            {
                const int rlo = tid >> 4, sl = tid & 15;
                #pragma unroll
                for (int p = 0; p < 4; ++p) {
                    const int r    = p * 32 + rlo;
                    const int srow = list[r < nc ? r : 0];
                    const int sc   = (sl ^ (r & 7)) << 4;
                    load16_to_lds((const char*)en + (size_t)srow * 256 + sc,
                                  (char*)Abuf + r * 256 + sl * 16);
                }
            }
            __syncthreads();

            const int wr = wid >> 1;      // 0..3
            const int wc = wid & 1;       // 0..1
            short8 a[2][4];
            #pragma unroll
            for (int m = 0; m < 2; ++m)
                #pragma unroll
                for (int ks = 0; ks < 4; ++ks)
                    a[m][ks] = read_frag(Abuf, wr * 32 + m * 16 + lm, hi + ks * 4);

            f32x4 acc[2][4] = {};
            #pragma unroll
            for (int ks = 0; ks < 4; ++ks) {
                short8 b[4];
                #pragma unroll
                for (int nn = 0; nn < 4; ++nn)
                    b[nn] = read_frag(Abuf, wc * 64 + nn * 16 + lm, hi + ks * 4);
                #pragma unroll
                for (int m = 0; m < 2; ++m)
                    #pragma unroll
                    for (int nn = 0; nn < 4; ++nn)
                        acc[m][nn] = __builtin_amdgcn_mfma_f32_16x16x32_bf16(a[m][ks], b[nn], acc[m][nn], 0, 0, 0);
            }

            #pragma unroll
            for (int m = 0; m < 2; ++m)
                #pragma unroll
                for (int nn = 0; nn < 4; ++nn) {
                    const int v = wc * 64 + nn * 16 + lm;
                    #pragma unroll
                    for (int r = 0; r < 4; ++r) {
                        const int u = wr * 32 + m * 16 + rb + r;
                        const float s = acc[m][nn][r];
                        const float t = (1.0f - s) - fmaxf(s - MARGIN, 0.0f);
                        csum += (u < v && v < nc) ? t : 0.0f;
                    }
                }
        } else {
            __syncthreads();   // uniform barrier count
        }

        #pragma unroll
        for (int o = 32; o; o >>= 1) csum += __shfl_down(csum, o, 64);
        if (lane == 0) wsum[wid] = csum;
        __syncthreads();
        if (tid == 0) {
            float b = 0.0f;
            #pragma unroll
            for (int w = 0; w < 8; ++w) b += wsum[w];
            partials[blockIdx.x] = b;
        }
        return;
    }

    // ================= GEMM block (label-blind), XCD-bijective swizzle =================
    {
        const int graw = (int)blockIdx.x - NLAB;     // 0..543 ; 544 = 8*68
        int t = (graw & 7) * 68 + (graw >> 3);       // same-XCD -> contiguous band
        int bi = 0, cnt = (nt + CHUNK - 1) / CHUNK;
        #pragma unroll 1
        while (t >= cnt) { t -= cnt; ++bi; cnt = (nt - bi + CHUNK - 1) / CHUNK; }
        const int jbase = bi + t * CHUNK;
        const int jb128 = jbase * 128;
        const int nsub  = 2 * min(CHUNK, nt - jbase);

        const int wr = wid >> 1;            // 0..3: 32-row band
        const int wc = wid & 1;             // 0..1: 32-col half

        // single-drain prologue: A strip + B0 staged together
        stage64(en, bi * 128,      Abuf,            tid);
        stage64(en, bi * 128 + 64, Abuf + 64 * DIM, tid);
        stage64(en, jb128,         &buf[0][0],      tid);
        const int r0w = bi * 128 + wr * 32;
        __syncthreads();                    // ONE drain: A + B0 ready

        short8 a[2][4];
        #pragma unroll
        for (int m = 0; m < 2; ++m)
            #pragma unroll
            for (int ks = 0; ks < 4; ++ks)
                a[m][ks] = read_frag(Abuf, wr * 32 + m * 16 + lm, hi + ks * 4);

        f32x4 vsum = (f32x4){0.0f, 0.0f, 0.0f, 0.0f};
        #pragma unroll 1
        for (int s = 0; s < nsub; ++s) {
            const short* cur = &buf[s & 1][0];
            if (s + 1 < nsub)
                stage64(en, jb128 + (s + 1) * 64, &buf[(s + 1) & 1][0], tid);

            f32x4 acc[2][2] = {};
            #pragma unroll
            for (int ks = 0; ks < 4; ++ks) {
                short8 b[2];
                b[0] = read_frag(cur, wc * 32 + lm,      hi + ks * 4);
                b[1] = read_frag(cur, wc * 32 + 16 + lm, hi + ks * 4);
                #pragma unroll
                for (int m = 0; m < 2; ++m)
                    #pragma unroll
                    for (int n = 0; n < 2; ++n)
                        acc[m][n] = __builtin_amdgcn_mfma_f32_16x16x32_bf16(a[m][ks], b[n], acc[m][n], 0, 0, 0);
            }

            if ((jbase == bi) && (s < 2)) {            // diagonal subtile: strict i<j
                const int c0 = jb128 + s * 64 + wc * 32;
                #pragma unroll
                for (int m = 0; m < 2; ++m)
                    #pragma unroll
                    for (int n = 0; n < 2; ++n) {
                        const f32x4 sv = acc[m][n] - MARGIN;
                        const int jj = c0 + n * 16 + lm;
                        #pragma unroll
                        for (int r = 0; r < 4; ++r) {
                            const int ii = r0w + m * 16 + rb + r;
                            vsum[r] += (ii < jj) ? fmaxf(sv[r], 0.0f) : 0.0f;
                        }
                    }
            } else {
                #pragma unroll
                for (int m = 0; m < 2; ++m)
                    #pragma unroll
                    for (int n = 0; n < 2; ++n) {
                        const f32x4 sv = acc[m][n] - MARGIN;
                        #pragma unroll
                        for (int r = 0; r < 4; ++r)
                            vsum[r] += fmaxf(sv[r], 0.0f);
                    }
            }
            __syncthreads();   // drains stage(s+1) + all reads of buf[s&1]
        }

        float lsum = vsum[0] + vsum[1] + vsum[2] + vsum[3];
        #pragma unroll
        for (int off = 32; off; off >>= 1) lsum += __shfl_down(lsum, off, 64);
        if (lane == 0) wsum[wid] = lsum;
        __syncthreads();
        if (tid == 0) {
            float b = 0.0f;
            #pragma unroll
            for (int w = 0; w < 8; ++w) b += wsum[w];
            partials[blockIdx.x] = b;
        }
    }
}

// ---------------- K3: final deterministic reduce ----------------
__global__ void __launch_bounds__(256) final_reduce_kernel(const float* __restrict__ partials,
                                                           float* __restrict__ out,
                                                           int n, float inv_denom) {
    float s = 0.0f;
    for (int i = threadIdx.x; i < n; i += 256) s += partials[i];
    #pragma unroll
    for (int off = 32; off; off >>= 1) s += __shfl_xor(s, off, 64);
    __shared__ float wsum[4];
    if ((threadIdx.x & 63) == 0) wsum[threadIdx.x >> 6] = s;
    __syncthreads();
    if (threadIdx.x == 0) out[0] = (wsum[0] + wsum[1] + wsum[2] + wsum[3]) * inv_denom;
}

extern "C" void kernel_launch(void* const* d_in, const int* in_sizes, int n_in,
                              void* d_out, int out_size, void* d_ws, size_t ws_size,
                              hipStream_t stream) {
    const float* emb    = (const float*)d_in[0];
    const int*   labels = (const int*)d_in[1];
    float*       out    = (float*)d_out;

    const int n  = in_sizes[1];      // 8192
    const int nt = n / 128;          // 64 strips

    int Tc = 0;                      // 544 GEMM blocks at CHUNK=4
    for (int i = 0; i < nt; ++i) Tc += (nt - i + CHUNK - 1) / CHUNK;

    unsigned int* en_packed = (unsigned int*)d_ws;
    short*        en        = (short*)d_ws;
    float*        partials  = (float*)((char*)d_ws + (size_t)n * DIM * 2);  // NLAB+Tc

    norm_bf16_kernel<<<n / 4, 256, 0, stream>>>(emb, en_packed);

    fused_kernel<<<NLAB + Tc, 512, 0, stream>>>(en, labels, n, partials, nt);

    const float inv_denom = (float)(1.0 / ((double)n * (double)(n - 1)));
    final_reduce_kernel<<<1, 256, 0, stream>>>(partials, out, NLAB + Tc, inv_denom);
}